// Round 5
// baseline (6663.760 us; speedup 1.0000x reference)
//
#include <hip/hip_runtime.h>
#include <hip/hip_fp16.h>

// LSTM forecaster: B=256, T=512, D_IN=64, H=1024, out = h_final @ Wout + bout.
// Round 5: XCD-LOCAL dataflow. 8 m-groups (32 batch rows each) of 32 WGs, each
// group confined to ONE XCD (guaranteed: 86KB LDS -> 1 WG/CU; cooperative launch
// of 256 WGs on 256 CUs -> bijection -> exactly 32 WGs per XCD; WGs self-organize
// via s_getreg(HW_REG_XCC_ID) + roster atomic).
//  - WG tile: 32 rows x 128 gate cols (32 units). W register-resident (136 VGPR).
//  - h exchange entirely through the XCD's L2: producer stores sc0 (write-through
//    L2), consumer loads sc0 (L1-bypass, L2-served). NO fences, NO L2 invalidates.
//  - NO grid barrier: per-producer monotonic flags (agent-scope atomics, proven);
//    flag set after vmcnt-drain => flag-visible implies h-in-L2. Double-buffered h
//    is safe: flag(t+1) also certifies the peer finished reading slot (t-1)&1.
//  - A = [x(t) | h(t-1)] staged in LDS [136][32][8] fp16, shared by all 8 waves;
//    waves = 4 col-subgroups x 2 K-halves; one-plane LDS reduce for the K-halves.

#define T_STEPS 512
#define GRID 256
#define NTHR 512

typedef __attribute__((ext_vector_type(8))) _Float16 half8;
typedef __attribute__((ext_vector_type(4))) float f32x4;
typedef __attribute__((ext_vector_type(4))) unsigned int u32x4;
typedef __attribute__((ext_vector_type(2))) unsigned int u32x2;

__device__ __forceinline__ float sigm(float v) { return __builtin_amdgcn_rcpf(1.0f + __expf(-v)); }
__device__ __forceinline__ float tanh_fast(float v) {
    return 2.0f * __builtin_amdgcn_rcpf(1.0f + __expf(-2.0f * v)) - 1.0f;
}

__device__ __forceinline__ u32x4 load16_sc0(const void* p) {
    u32x4 r;
    asm volatile("global_load_dwordx4 %0, %1, off sc0" : "=v"(r) : "v"(p) : "memory");
    return r;
}
__device__ __forceinline__ void store8_sc0(void* p, u32x2 v) {
    asm volatile("global_store_dwordx2 %0, %1, off sc0" ::"v"(p), "v"(v) : "memory");
}
__device__ __forceinline__ void wait_vm0() { asm volatile("s_waitcnt vmcnt(0)" ::: "memory"); }
__device__ __forceinline__ void wait_lgkm0() { asm volatile("s_waitcnt lgkmcnt(0)" ::: "memory"); }

// Pack W [1088][4096] f32 -> Wp fp16 [n(32)][kb(136)][col(128)][8]
// col c of group n -> original column (c&3)*1024 + n*32 + (c>>2) (gate-interleaved).
__global__ void pack_w(const float* __restrict__ W, _Float16* __restrict__ Wp) {
    int idx = blockIdx.x * 256 + threadIdx.x;
    const int total = 32 * 136 * 128;
    if (idx >= total) return;
    int col = idx & 127;
    int kb = (idx >> 7) % 136;
    int n = (idx >> 7) / 136;
    int oc = ((col & 3) << 10) + (n << 5) + (col >> 2);
    const float* src = W + (size_t)(kb * 8) * 4096 + oc;
    _Float16* dst = Wp + (size_t)idx * 8;
#pragma unroll
    for (int j = 0; j < 8; j++) dst[j] = (_Float16)src[(size_t)j * 4096];
}

extern __shared__ char smem[];  // A: [0,69632) fp16 [136][32][8]; P: [69632,86016) f32 [4][32][32]

__global__ void __launch_bounds__(NTHR, 2) lstm_persist(
    const float* __restrict__ x,      // [256][512][64] f32
    const _Float16* __restrict__ Wp,  // packed W fp16
    const float* __restrict__ bias,   // [4096] f32
    _Float16* __restrict__ hbuf,      // [2][m(8)][ub(128)][r(32)][8] fp16
    float* __restrict__ hfinal,       // [256][1024] f32
    unsigned int* ctrl)               // flags [256]x64B at 0; roster [8]x64B at 16384B
{
    __shared__ int mn_sh[2];
    _Float16* A = (_Float16*)smem;
    float* P = (float*)(smem + 69632);

    int tid = threadIdx.x;
    int w = tid >> 6;
    int lane = tid & 63;
    int l15 = lane & 15, l4 = lane >> 4;
    int nsub = w & 3, kh = w >> 2;
    int r = lane & 31, hi = lane >> 5;  // activation coords

    // ---- self-organize: (m = physical XCD, n = rank 0..31 within it) ----
    if (tid == 0) {
        unsigned q;
        asm volatile("s_getreg_b32 %0, hwreg(HW_REG_XCC_ID)" : "=s"(q));
        q &= 7u;
        unsigned rk = __hip_atomic_fetch_add(ctrl + 4096 + q * 16, 1u, __ATOMIC_RELAXED,
                                             __HIP_MEMORY_SCOPE_AGENT);
        mn_sh[0] = (int)q;
        mn_sh[1] = (int)rk;
    }
    __syncthreads();
    const int m = mn_sh[0], n = mn_sh[1];

    // ---- W prologue: this wave's K-half x col-subgroup, register-resident ----
    half8 wf[17][2];
    {
        const _Float16* wb = Wp + (size_t)n * 136 * 128 * 8;
#pragma unroll
        for (int ch = 0; ch < 17; ch++) {
            int kb = (kh * 17 + ch) * 4 + l4;
#pragma unroll
            for (int nf = 0; nf < 2; nf++) {
                int col = nsub * 32 + nf * 16 + l15;
                wf[ch][nf] = *(const half8*)(wb + ((size_t)kb * 128 + col) * 8);
            }
        }
    }

    // per-lane bias (kh0 waves do activations): unit = 32n + 8*nsub + 4*hi + k
    float breg[4][4];
#pragma unroll
    for (int k = 0; k < 4; k++)
#pragma unroll
        for (int g = 0; g < 4; g++)
            breg[k][g] = bias[(g << 10) + (n << 5) + (nsub << 3) + (hi << 2) + k];
    float cst[4] = {0.f, 0.f, 0.f, 0.f};

    // x(tt) -> A[0..7][r][8] fp16, by threads 256..511
    auto XSTAGE = [&](int tt) {
        if (tid >= 256) {
            int i = tid - 256;
            int kb = i >> 5, rr = i & 31;
            const float* xp = x + ((size_t)(32 * m + rr) * T_STEPS + tt) * 64 + kb * 8;
            f32x4 lo = *(const f32x4*)xp;
            f32x4 hx = *(const f32x4*)(xp + 4);
            half8 v;
            v[0] = (_Float16)lo[0]; v[1] = (_Float16)lo[1];
            v[2] = (_Float16)lo[2]; v[3] = (_Float16)lo[3];
            v[4] = (_Float16)hx[0]; v[5] = (_Float16)hx[1];
            v[6] = (_Float16)hx[2]; v[7] = (_Float16)hx[3];
            *(half8*)&A[((kb << 5) + rr) << 3] = v;
        }
    };

    // h(slot) -> A[8..135][32][8], sc0 loads (L1-bypass, L2-served), 8x16B/thread
    auto HSTAGE = [&](int slot) {
        const char* hsrc = (const char*)hbuf + (size_t)(slot * 8 + m) * 65536;
        size_t t16 = (size_t)tid * 16;
        u32x4 s0 = load16_sc0(hsrc + t16);
        u32x4 s1 = load16_sc0(hsrc + 8192 + t16);
        u32x4 s2 = load16_sc0(hsrc + 16384 + t16);
        u32x4 s3 = load16_sc0(hsrc + 24576 + t16);
        u32x4 s4 = load16_sc0(hsrc + 32768 + t16);
        u32x4 s5 = load16_sc0(hsrc + 40960 + t16);
        u32x4 s6 = load16_sc0(hsrc + 49152 + t16);
        u32x4 s7 = load16_sc0(hsrc + 57344 + t16);
        wait_vm0();
        char* d = (char*)A + 4096 + t16;
        *(u32x4*)(d) = s0;          *(u32x4*)(d + 8192) = s1;
        *(u32x4*)(d + 16384) = s2;  *(u32x4*)(d + 24576) = s3;
        *(u32x4*)(d + 32768) = s4;  *(u32x4*)(d + 40960) = s5;
        *(u32x4*)(d + 49152) = s6;  *(u32x4*)(d + 57344) = s7;
    };

    // ---- prologue: stage x(0) and h(-1)=zeros (slot 1) ----
    XSTAGE(0);
    HSTAGE(1);
    __syncthreads();

    for (int t = 0; t < T_STEPS; t++) {
        const int slot = t & 1;

        // ---- K loop: all waves, A from LDS, W from registers ----
        f32x4 acc[2][2];
#pragma unroll
        for (int a = 0; a < 2; a++)
#pragma unroll
            for (int b = 0; b < 2; b++) acc[a][b] = (f32x4){0.f, 0.f, 0.f, 0.f};
#pragma unroll
        for (int ch = 0; ch < 17; ch++) {
            int kb = (kh * 17 + ch) * 4 + l4;
            half8 a0 = *(const half8*)&A[(((kb << 5) + l15) << 3)];
            half8 a1 = *(const half8*)&A[(((kb << 5) + 16 + l15) << 3)];
            acc[0][0] = __builtin_amdgcn_mfma_f32_16x16x32_f16(a0, wf[ch][0], acc[0][0], 0, 0, 0);
            acc[0][1] = __builtin_amdgcn_mfma_f32_16x16x32_f16(a0, wf[ch][1], acc[0][1], 0, 0, 0);
            acc[1][0] = __builtin_amdgcn_mfma_f32_16x16x32_f16(a1, wf[ch][0], acc[1][0], 0, 0, 0);
            acc[1][1] = __builtin_amdgcn_mfma_f32_16x16x32_f16(a1, wf[ch][1], acc[1][1], 0, 0, 0);
        }
        __syncthreads();  // S1: A reads done, prev P usage done

        if (kh == 1) {
            // K-half-1 partials -> P (XOR-swizzled rows, conflict-free-ish)
#pragma unroll
            for (int mf = 0; mf < 2; mf++)
#pragma unroll
                for (int nf = 0; nf < 2; nf++) {
                    int lc = nf * 16 + l15;
                    int rr = ((mf << 4) + (l4 << 2)) ^ ((l15 & 7) << 2);
                    *(f32x4*)&P[((nsub << 5) + lc) * 32 + rr] = acc[mf][nf];
                }
            if (t + 1 < T_STEPS) XSTAGE(t + 1);  // x is h-independent
        }
        __syncthreads();  // S2

        if (kh == 0) {
            // add K-half-1, write back summed gates; in-wave act via LDS bounce
#pragma unroll
            for (int mf = 0; mf < 2; mf++)
#pragma unroll
                for (int nf = 0; nf < 2; nf++) {
                    int lc = nf * 16 + l15;
                    int rr = ((mf << 4) + (l4 << 2)) ^ ((l15 & 7) << 2);
                    float* pp = &P[((nsub << 5) + lc) * 32 + rr];
                    f32x4 v = *(f32x4*)pp;
                    v += acc[mf][nf];
                    *(f32x4*)pp = v;
                }
            wait_lgkm0();
            union { _Float16 h[4]; u32x2 u; } hp;
            float hout[4];
#pragma unroll
            for (int k = 0; k < 4; k++) {
                float g4[4];
#pragma unroll
                for (int g = 0; g < 4; g++) {
                    int lc = ((hi << 2) + k) * 4 + g;
                    g4[g] = breg[k][g] + P[((nsub << 5) + lc) * 32 + (r ^ ((lc & 7) << 2))];
                }
                float ig = sigm(g4[0]);
                float fg = sigm(g4[1]);
                float gg = tanh_fast(g4[2]);
                float og = sigm(g4[3]);
                float cv = fg * cst[k] + ig * gg;
                cst[k] = cv;
                float hv = og * tanh_fast(cv);
                hp.h[k] = (_Float16)hv;
                hout[k] = hv;
            }
            if (t == T_STEPS - 1) {
                f32x4 hv4 = {hout[0], hout[1], hout[2], hout[3]};
                *(f32x4*)&hfinal[(size_t)(32 * m + r) * 1024 + (n << 5) + (nsub << 3) + (hi << 2)] = hv4;
            } else {
                size_t off = ((size_t)((slot * 8 + m) * 128 + (n << 2) + nsub) * 32 + r) * 16 + (hi << 3);
                store8_sc0((char*)hbuf + off, hp.u);
                wait_vm0();  // h(t) in L2 before this wave arrives at S3a
            }
        }
        if (t == T_STEPS - 1) break;  // uniform
        __syncthreads();  // S3a: all h-stores of this WG are in L2

        if (tid == 0)
            __hip_atomic_store(ctrl + (m * 32 + n) * 16, (unsigned int)(t + 1), __ATOMIC_RELAXED,
                               __HIP_MEMORY_SCOPE_AGENT);
        if (w == 7) {
            // wait for all 32 producers of this XCD group
            const unsigned int* ap = ctrl + (m * 32 + (lane & 31)) * 16;
            bool done = (lane >= 32);
            unsigned int tgt = (unsigned int)(t + 1);
            while (!__all(done)) {
                if (!done)
                    done = (__hip_atomic_load(ap, __ATOMIC_RELAXED, __HIP_MEMORY_SCOPE_AGENT) >= tgt);
                if (!done) __builtin_amdgcn_s_sleep(1);
            }
        }
        __syncthreads();  // S3b: group ready

        HSTAGE(slot);     // h(t) -> LDS for step t+1
        __syncthreads();  // S4
    }
}

// out[b][j] = bout[j] + sum_k hfinal[b][k] * Wout[k][j]   (256 blocks x 64 threads)
__global__ void proj_kernel(const float* __restrict__ hfinal, const float* __restrict__ Wout,
                            const float* __restrict__ bout, float* __restrict__ out) {
    int b = blockIdx.x;
    int l = threadIdx.x;
    float acc[24];
#pragma unroll
    for (int j = 0; j < 24; j++) acc[j] = 0.f;
    for (int i = 0; i < 16; i++) {
        int k = i * 64 + l;
        float h = hfinal[(size_t)b * 1024 + k];
        const float* wr = Wout + (size_t)k * 24;
#pragma unroll
        for (int j = 0; j < 24; j++) acc[j] += h * wr[j];
    }
    __shared__ float red[24][65];
#pragma unroll
    for (int j = 0; j < 24; j++) red[j][l] = acc[j];
    __syncthreads();
    if (l < 24) {
        float s = bout[l];
#pragma unroll
        for (int i = 0; i < 64; i++) s += red[l][i];
        out[b * 24 + l] = s;
    }
}

extern "C" void kernel_launch(void* const* d_in, const int* in_sizes, int n_in,
                              void* d_out, int out_size, void* d_ws, size_t ws_size,
                              hipStream_t stream) {
    const float* x = (const float*)d_in[0];     // [256][512][64]
    const float* W = (const float*)d_in[1];     // [1088][4096]
    const float* b = (const float*)d_in[2];     // [4096]
    const float* Wout = (const float*)d_in[3];  // [1024][24]
    const float* bout = (const float*)d_in[4];  // [24]
    float* out = (float*)d_out;

    char* ws = (char*)d_ws;
    _Float16* Wp = (_Float16*)ws;                              // 8,912,896 B
    _Float16* hbuf = (_Float16*)(ws + 8912896);                // 1,048,576 B
    float* hfinal = (float*)(ws + 8912896 + 1048576);          // 1,048,576 B
    unsigned int* ctrl = (unsigned int*)(ws + 8912896 + 2097152);  // 32,768 B

    // zero h slot 1 (h_init) + flags/roster every call (graph-replay safe)
    hipMemsetAsync((char*)hbuf + 524288, 0, 524288, stream);
    hipMemsetAsync(ctrl, 0, 32768, stream);

    pack_w<<<(32 * 136 * 128 + 255) / 256, 256, 0, stream>>>(W, Wp);

    hipFuncSetAttribute((const void*)lstm_persist, hipFuncAttributeMaxDynamicSharedMemorySize,
                        86016);

    void* args[6];
    args[0] = (void*)&x;
    args[1] = (void*)&Wp;
    args[2] = (void*)&b;
    args[3] = (void*)&hbuf;
    args[4] = (void*)&hfinal;
    args[5] = (void*)&ctrl;
    hipLaunchCooperativeKernel((void*)lstm_persist, dim3(GRID), dim3(NTHR), args, 86016, stream);

    proj_kernel<<<256, 64, 0, stream>>>(hfinal, Wout, bout, out);
}

// Round 10
// 3560.801 us; speedup vs baseline: 1.8714x; 1.8714x over previous
//
#include <hip/hip_runtime.h>
#include <hip/hip_fp16.h>

// LSTM forecaster: B=256, T=512, D_IN=64, H=1024, out = h_final @ Wout + bout.
// Round 10 = Round 3 (last PASSING config, 3.69ms) + packed h-stores rebuilt from
// session-PROVEN primitives only.
// Post-mortem chain: R8 abort blamed on 67.5KB static LDS; R9 removed that and
// STILL aborted -> the sc0 sc1 inline-asm global ops (present in both R8+R9,
// absent from every passing round) are the indicted element. Lesson: no
// hand-rolled cache-bit asm; only intrinsic atomics (R2-R5-proven).
// Changes vs R3:
//  - h stores: all threads stage 4B into a 2KB LDS tile (overlaid on P plane 0,
//    behind a barrier that closes all P reads); 128 threads then publish dense
//    16B (2x u64 agent-scope atomic stores, consecutive) -> kills R3's 4x
//    WRITE_SIZE amplification (1.06GB for 262MB payload), 16x fewer MALL store
//    requests (2048 -> 256 per WG/step... 128 threads x 2).
//  - h loads, flags, poll, XPREP overlap: byte-identical to R3.

#define T_STEPS 512
#define HID 1024
#define GRID 256
#define NTHR 512

typedef __attribute__((ext_vector_type(8))) _Float16 half8;
typedef __attribute__((ext_vector_type(4))) float f32x4;
typedef __attribute__((ext_vector_type(2))) float f32x2;

__device__ __forceinline__ float sigm(float v) {
    return __builtin_amdgcn_rcpf(1.0f + __expf(-v));
}
__device__ __forceinline__ float tanh_fast(float v) {
    return 2.0f * __builtin_amdgcn_rcpf(1.0f + __expf(-2.0f * v)) - 1.0f;
}

// Pack W [1088][4096] f32 -> Wp fp16 [n(64)][kb(136)][col(64)][kin(8)]
// col c of group n maps to original column (c&3)*1024 + n*16 + (c>>2)  (gate-interleaved).
__global__ void pack_w(const float* __restrict__ W, _Float16* __restrict__ Wp) {
    int idx = blockIdx.x * 256 + threadIdx.x;
    const int total = 64 * 136 * 64;
    if (idx >= total) return;
    int col = idx & 63;
    int kb = (idx >> 6) % 136;
    int n = (idx >> 6) / 136;
    int oc = ((col & 3) << 10) + (n << 4) + (col >> 2);
    const float* src = W + (size_t)(kb * 8) * 4096 + oc;
    _Float16* dst = Wp + (size_t)idx * 8;
#pragma unroll
    for (int j = 0; j < 8; j++) dst[j] = (_Float16)src[(size_t)j * 4096];
}

__global__ void __launch_bounds__(NTHR, 2) lstm_persist(
    const float* __restrict__ x,      // [256][512][64] f32
    const _Float16* __restrict__ Wp,  // packed W fp16
    const float* __restrict__ bias,   // [4096] f32
    _Float16* __restrict__ hbuf,      // [2][128][256][8] fp16  (kb, b, kin)
    float* __restrict__ hfinal,       // [256][1024] f32
    unsigned int* bar)                // [256] arrival words, 64B apart
{
    __shared__ float P[4 * 64 * 64];  // 64 KiB (R3-proven size)
    _Float16* hstage = (_Float16*)P;  // 2 KiB overlay on plane 0 ([64][16])

    int wg = blockIdx.x;
    // XCD-aware mapping: XCD x gets n in [8x,8x+8) for all 4 m.
    int xcd = wg & 7, slot = wg >> 3;
    int n = (xcd << 3) + (slot & 7);  // 0..63
    int m = slot >> 3;                 // 0..3
    int B0 = m << 6;

    int tid = threadIdx.x;
    int wave = tid >> 6;   // 0..7
    int lane = tid & 63;
    int l15 = lane & 15, l4 = lane >> 4;
    int bb = tid & 63;
    int u0 = tid >> 6;     // activation: units 2*u0, 2*u0+1

    // per-thread bias: q -> (b=bb, u=2*u0+q), gates i,f,g,o
    float breg[2][4];
#pragma unroll
    for (int q = 0; q < 2; q++) {
        int u = (u0 << 1) + q;
#pragma unroll
        for (int g = 0; g < 4; g++) breg[q][g] = bias[(g << 10) + (n << 4) + u];
    }

    float cst[2] = {0.f, 0.f};

    const size_t HB = (size_t)128 * 256 * 8;
    const _Float16* WpBase = Wp + (size_t)n * 136 * 64 * 8;

    // ---- W prologue: wave w owns h-chunks {2+w, 10+w, 18+w, 26+w} (covers 2..33),
    //      fragments register-resident for all 512 steps ----
    half8 wfr[4][4];
#pragma unroll
    for (int j = 0; j < 4; j++) {
        int kb = ((2 + wave + 8 * j) << 2) + l4;  // 8..135
        const _Float16* wp = WpBase + ((size_t)kb << 9);
#pragma unroll
        for (int nn = 0; nn < 4; nn++) wfr[j][nn] = *(const half8*)(wp + (((nn << 4) + l15) << 3));
    }

    f32x4 acc[4][4];
#pragma unroll
    for (int i = 0; i < 4; i++)
#pragma unroll
        for (int j = 0; j < 4; j++) acc[i][j] = (f32x4){0.f, 0.f, 0.f, 0.f};

    // x(tt) @ Wx into acc — waves 2,3 only (x chunk = wave-2, k in [32(w-2), 32(w-2)+32))
    auto XPREP = [&](int tt) {
        if (wave == 2 || wave == 3) {
            int kb = ((wave - 2) << 2) + l4;  // 0..7
            half8 bx[4];
            const _Float16* wp = WpBase + ((size_t)kb << 9);
#pragma unroll
            for (int nn = 0; nn < 4; nn++) bx[nn] = *(const half8*)(wp + (((nn << 4) + l15) << 3));
#pragma unroll
            for (int mm = 0; mm < 4; mm++) {
                const float* xp = x + ((size_t)(B0 + (mm << 4) + l15) * T_STEPS + tt) * 64 + (kb << 3);
                f32x4 lo = *(const f32x4*)xp;
                f32x4 hi = *(const f32x4*)(xp + 4);
                half8 v;
                v[0] = (_Float16)lo[0]; v[1] = (_Float16)lo[1];
                v[2] = (_Float16)lo[2]; v[3] = (_Float16)lo[3];
                v[4] = (_Float16)hi[0]; v[5] = (_Float16)hi[1];
                v[6] = (_Float16)hi[2]; v[7] = (_Float16)hi[3];
#pragma unroll
                for (int nn = 0; nn < 4; nn++)
                    acc[mm][nn] = __builtin_amdgcn_mfma_f32_16x16x32_f16(v, bx[nn], acc[mm][nn], 0, 0, 0);
            }
        }
    };

    XPREP(0);

    for (int t = 0; t < T_STEPS; t++) {
        const _Float16* cur = hbuf + (size_t)(t & 1) * HB;
        _Float16* nxt = hbuf + (size_t)((t + 1) & 1) * HB;

        // ---- h @ Wh: coherent (MALL) u64 atomic loads x2 per frag (R3-proven) ----
#pragma unroll
        for (int j = 0; j < 4; j++) {
            int kb = ((2 + wave + 8 * j) << 2) + l4;  // 8..135
            unsigned long long* hp =
                (unsigned long long*)(cur + (((size_t)(kb - 8) << 8) + B0 + l15) * 8);
            half8 ah[4];
#pragma unroll
            for (int mm = 0; mm < 4; mm++) {
                union { unsigned long long u[2]; half8 h; } cv;
                cv.u[0] = __hip_atomic_load(hp + (mm << 5), __ATOMIC_RELAXED, __HIP_MEMORY_SCOPE_AGENT);
                cv.u[1] = __hip_atomic_load(hp + (mm << 5) + 1, __ATOMIC_RELAXED, __HIP_MEMORY_SCOPE_AGENT);
                ah[mm] = cv.h;
            }
#pragma unroll
            for (int mm = 0; mm < 4; mm++)
#pragma unroll
                for (int nn = 0; nn < 4; nn++)
                    acc[mm][nn] = __builtin_amdgcn_mfma_f32_16x16x32_f16(ah[mm], wfr[j][nn],
                                                                         acc[mm][nn], 0, 0, 0);
        }

        // ---- two-pass cross-wave reduction, 4 planes of 16KB, XOR-swizzled ----
        if (wave < 4) {
#pragma unroll
            for (int mm = 0; mm < 4; mm++)
#pragma unroll
                for (int nn = 0; nn < 4; nn++) {
                    int c = (nn << 4) + l15;
                    int bblk = (mm << 2) + l4;
                    int word = (((wave << 6) + c) << 6) + (((bblk ^ l15) & 15) << 2);
                    *(f32x4*)&P[word] = acc[mm][nn];
                }
        }
        __syncthreads();
        if (wave >= 4) {
            int pw = wave - 4;
#pragma unroll
            for (int mm = 0; mm < 4; mm++)
#pragma unroll
                for (int nn = 0; nn < 4; nn++) {
                    int c = (nn << 4) + l15;
                    int bblk = (mm << 2) + l4;
                    int word = (((pw << 6) + c) << 6) + (((bblk ^ l15) & 15) << 2);
                    f32x4 v = *(f32x4*)&P[word];
                    v += acc[mm][nn];
                    *(f32x4*)&P[word] = v;
                }
        }
        __syncthreads();

        // ---- activations: thread handles (b=bb, u=2*u0+q), q=0,1 ----
        union { _Float16 h2[2]; unsigned int u; } hs;
        float hvf[2];
#pragma unroll
        for (int q = 0; q < 2; q++) {
            int u = (u0 << 1) + q;
            float g4[4];
#pragma unroll
            for (int g = 0; g < 4; g++) {
                int c = (u << 2) + g;
                int word = (c << 6) + (((((bb >> 2) ^ c) & 15) << 2) | (bb & 3));
                float s = breg[q][g];
#pragma unroll
                for (int w = 0; w < 4; w++) s += P[(w << 12) + word];
                g4[g] = s;
            }
            float ig = sigm(g4[0]);
            float fg = sigm(g4[1]);
            float gg = tanh_fast(g4[2]);
            float og = sigm(g4[3]);
            float cv = fg * cst[q] + ig * gg;
            cst[q] = cv;
            float hv = og * tanh_fast(cv);
            hs.h2[q] = (_Float16)hv;
            hvf[q] = hv;
        }
        if (t == T_STEPS - 1) {
            int ug0 = (n << 4) + (u0 << 1);
            f32x2 hv2; hv2[0] = hvf[0]; hv2[1] = hvf[1];
            *(f32x2*)&hfinal[(size_t)(B0 + bb) * HID + ug0] = hv2;
            break;  // uniform; no h publish after last step
        }

        // ---- packed h publish: 4B -> overlay tile -> 128 threads x 2 u64 atomic stores ----
        __syncthreads();  // S_act: ALL P reads complete before overlay writes
        *(unsigned int*)&hstage[(bb << 4) + (u0 << 1)] = hs.u;
        __syncthreads();  // S_pack: overlay tile complete
        if (tid < 128) {
            int row = tid >> 1, hf = tid & 1;  // batch row, 8-unit half
            union { half8 h; unsigned long long u[2]; } v;
            v.h = *(const half8*)&hstage[(row << 4) + (hf << 3)];
            // dst: hbuf[nxt][kb'=2n+hf][B0+row][0..7] (16B, 8B-aligned)
            unsigned long long* dst =
                (unsigned long long*)(nxt + (((size_t)((n << 1) + hf) << 8) + B0 + row) * 8);
            __hip_atomic_store(dst, v.u[0], __ATOMIC_RELAXED, __HIP_MEMORY_SCOPE_AGENT);
            __hip_atomic_store(dst + 1, v.u[1], __ATOMIC_RELAXED, __HIP_MEMORY_SCOPE_AGENT);
        }
        asm volatile("s_waitcnt vmcnt(0)" ::: "memory");  // h(t) ack'd at MALL (R3-proven)
        __syncthreads();  // S3a: all packed stores complete

        if (tid == 0)
            __hip_atomic_store(bar + (wg << 4), (unsigned int)(t + 1), __ATOMIC_RELAXED,
                               __HIP_MEMORY_SCOPE_AGENT);
        // reset acc and fold in x(t+1) while other WGs arrive
#pragma unroll
        for (int i = 0; i < 4; i++)
#pragma unroll
            for (int j = 0; j < 4; j++) acc[i][j] = (f32x4){0.f, 0.f, 0.f, 0.f};
        XPREP(t + 1);
        if (tid >= 256) {
            const unsigned int* ap = bar + ((tid - 256) << 4);
            while (__hip_atomic_load(ap, __ATOMIC_RELAXED, __HIP_MEMORY_SCOPE_AGENT) <
                   (unsigned int)(t + 1)) {
                __builtin_amdgcn_s_sleep(1);
            }
        }
        __syncthreads();
    }
}

// out[b][j] = bout[j] + sum_k hfinal[b][k] * Wout[k][j]   (256 blocks x 64 threads)
__global__ void proj_kernel(const float* __restrict__ hfinal, const float* __restrict__ Wout,
                            const float* __restrict__ bout, float* __restrict__ out) {
    int b = blockIdx.x;
    int l = threadIdx.x;
    float acc[24];
#pragma unroll
    for (int j = 0; j < 24; j++) acc[j] = 0.f;
    for (int i = 0; i < 16; i++) {
        int k = i * 64 + l;
        float h = hfinal[(size_t)b * HID + k];
        const float* wr = Wout + (size_t)k * 24;
#pragma unroll
        for (int j = 0; j < 24; j++) acc[j] += h * wr[j];
    }
    __shared__ float red[24][65];
#pragma unroll
    for (int j = 0; j < 24; j++) red[j][l] = acc[j];
    __syncthreads();
    if (l < 24) {
        float s = bout[l];
#pragma unroll
        for (int i = 0; i < 64; i++) s += red[l][i];
        out[b * 24 + l] = s;
    }
}

extern "C" void kernel_launch(void* const* d_in, const int* in_sizes, int n_in,
                              void* d_out, int out_size, void* d_ws, size_t ws_size,
                              hipStream_t stream) {
    const float* x = (const float*)d_in[0];     // [256][512][64]
    const float* W = (const float*)d_in[1];     // [1088][4096]
    const float* b = (const float*)d_in[2];     // [4096]
    const float* Wout = (const float*)d_in[3];  // [1024][24]
    const float* bout = (const float*)d_in[4];  // [24]
    float* out = (float*)d_out;

    char* ws = (char*)d_ws;
    _Float16* Wp = (_Float16*)ws;                                 // 8,912,896 B
    _Float16* hbuf = (_Float16*)(ws + 8912896);                   // 1,048,576 B
    float* hfinal = (float*)(ws + 8912896 + 1048576);             // 1,048,576 B
    unsigned int* bar = (unsigned int*)(ws + 8912896 + 2097152);  // 16,384 B

    // zero h buffer 0 (h_init = 0) and barrier words, every call (graph-replay safe)
    hipMemsetAsync(hbuf, 0, (size_t)128 * 256 * 8 * sizeof(_Float16), stream);
    hipMemsetAsync(bar, 0, 16384, stream);

    pack_w<<<(64 * 136 * 64 + 255) / 256, 256, 0, stream>>>(W, Wp);

    void* args[6];
    args[0] = (void*)&x;
    args[1] = (void*)&Wp;
    args[2] = (void*)&b;
    args[3] = (void*)&hbuf;
    args[4] = (void*)&hfinal;
    args[5] = (void*)&bar;
    hipLaunchCooperativeKernel((void*)lstm_persist, dim3(GRID), dim3(NTHR), args, 0, stream);

    proj_kernel<<<256, 64, 0, stream>>>(hfinal, Wout, bout, out);
}

// Round 11
// 3514.257 us; speedup vs baseline: 1.8962x; 1.0132x over previous
//
#include <hip/hip_runtime.h>
#include <hip/hip_fp16.h>

// LSTM forecaster: B=256, T=512, D_IN=64, H=1024, out = h_final @ Wout + bout.
// Round 11 = Round 10 (3.56ms, passed) + two proven-primitive refinements:
//  (1) Wx fragments register-resident in waves 2,3 (loaded once in prologue).
//      R10's FETCH_SIZE 1.24GB ~= XPREP re-reading the same 8KB/WG every step;
//      also shortens XPREP in the barrier shadow -> poll completes earlier.
//  (2) m-group-local barrier (R4-validated topology): consumer (m,n) only needs
//      producers wg in [64m,64m+64). One wave (threads 256..319) polls those 64
//      words -> 4x fewer polling lanes contending with h-loads at the MALL,
//      4 independent barriers absorb inter-group jitter.
// Everything else byte-identical to R10 (h loads 2x u64 agent atomics; packed
// 16B h publish via LDS overlay tile; agent-scope flags; XPREP overlap).

#define T_STEPS 512
#define HID 1024
#define GRID 256
#define NTHR 512

typedef __attribute__((ext_vector_type(8))) _Float16 half8;
typedef __attribute__((ext_vector_type(4))) float f32x4;
typedef __attribute__((ext_vector_type(2))) float f32x2;

__device__ __forceinline__ float sigm(float v) {
    return __builtin_amdgcn_rcpf(1.0f + __expf(-v));
}
__device__ __forceinline__ float tanh_fast(float v) {
    return 2.0f * __builtin_amdgcn_rcpf(1.0f + __expf(-2.0f * v)) - 1.0f;
}

// Pack W [1088][4096] f32 -> Wp fp16 [n(64)][kb(136)][col(64)][kin(8)]
// col c of group n maps to original column (c&3)*1024 + n*16 + (c>>2)  (gate-interleaved).
__global__ void pack_w(const float* __restrict__ W, _Float16* __restrict__ Wp) {
    int idx = blockIdx.x * 256 + threadIdx.x;
    const int total = 64 * 136 * 64;
    if (idx >= total) return;
    int col = idx & 63;
    int kb = (idx >> 6) % 136;
    int n = (idx >> 6) / 136;
    int oc = ((col & 3) << 10) + (n << 4) + (col >> 2);
    const float* src = W + (size_t)(kb * 8) * 4096 + oc;
    _Float16* dst = Wp + (size_t)idx * 8;
#pragma unroll
    for (int j = 0; j < 8; j++) dst[j] = (_Float16)src[(size_t)j * 4096];
}

__global__ void __launch_bounds__(NTHR, 2) lstm_persist(
    const float* __restrict__ x,      // [256][512][64] f32
    const _Float16* __restrict__ Wp,  // packed W fp16
    const float* __restrict__ bias,   // [4096] f32
    _Float16* __restrict__ hbuf,      // [2][128][256][8] fp16  (kb, b, kin)
    float* __restrict__ hfinal,       // [256][1024] f32
    unsigned int* bar)                // [256] arrival words, 64B apart
{
    __shared__ float P[4 * 64 * 64];  // 64 KiB (proven size)
    _Float16* hstage = (_Float16*)P;  // 2 KiB overlay on plane 0 ([64][16])

    int wg = blockIdx.x;
    // XCD-aware mapping: XCD x gets n in [8x,8x+8) for all 4 m.
    int xcd = wg & 7, slot = wg >> 3;
    int n = (xcd << 3) + (slot & 7);  // 0..63
    int m = slot >> 3;                 // 0..3  (m-group = wgs [64m, 64m+64))
    int B0 = m << 6;

    int tid = threadIdx.x;
    int wave = tid >> 6;   // 0..7
    int lane = tid & 63;
    int l15 = lane & 15, l4 = lane >> 4;
    int bb = tid & 63;
    int u0 = tid >> 6;     // activation: units 2*u0, 2*u0+1

    // per-thread bias: q -> (b=bb, u=2*u0+q), gates i,f,g,o
    float breg[2][4];
#pragma unroll
    for (int q = 0; q < 2; q++) {
        int u = (u0 << 1) + q;
#pragma unroll
        for (int g = 0; g < 4; g++) breg[q][g] = bias[(g << 10) + (n << 4) + u];
    }

    float cst[2] = {0.f, 0.f};

    const size_t HB = (size_t)128 * 256 * 8;
    const _Float16* WpBase = Wp + (size_t)n * 136 * 64 * 8;

    // ---- W prologue: wave w owns h-chunks {2+w, 10+w, 18+w, 26+w} (covers 2..33),
    //      fragments register-resident for all 512 steps ----
    half8 wfr[4][4];
#pragma unroll
    for (int j = 0; j < 4; j++) {
        int kb = ((2 + wave + 8 * j) << 2) + l4;  // 8..135
        const _Float16* wp = WpBase + ((size_t)kb << 9);
#pragma unroll
        for (int nn = 0; nn < 4; nn++) wfr[j][nn] = *(const half8*)(wp + (((nn << 4) + l15) << 3));
    }

    // ---- Wx prologue (NEW): waves 2,3 keep their x-chunk W fragments resident ----
    half8 bxr[4];
    if (wave == 2 || wave == 3) {
        int kb = ((wave - 2) << 2) + l4;  // 0..7
        const _Float16* wp = WpBase + ((size_t)kb << 9);
#pragma unroll
        for (int nn = 0; nn < 4; nn++) bxr[nn] = *(const half8*)(wp + (((nn << 4) + l15) << 3));
    }

    f32x4 acc[4][4];
#pragma unroll
    for (int i = 0; i < 4; i++)
#pragma unroll
        for (int j = 0; j < 4; j++) acc[i][j] = (f32x4){0.f, 0.f, 0.f, 0.f};

    // x(tt) @ Wx into acc — waves 2,3 only; W from registers, x cached loads
    auto XPREP = [&](int tt) {
        if (wave == 2 || wave == 3) {
            int kb = ((wave - 2) << 2) + l4;  // 0..7
#pragma unroll
            for (int mm = 0; mm < 4; mm++) {
                const float* xp = x + ((size_t)(B0 + (mm << 4) + l15) * T_STEPS + tt) * 64 + (kb << 3);
                f32x4 lo = *(const f32x4*)xp;
                f32x4 hi = *(const f32x4*)(xp + 4);
                half8 v;
                v[0] = (_Float16)lo[0]; v[1] = (_Float16)lo[1];
                v[2] = (_Float16)lo[2]; v[3] = (_Float16)lo[3];
                v[4] = (_Float16)hi[0]; v[5] = (_Float16)hi[1];
                v[6] = (_Float16)hi[2]; v[7] = (_Float16)hi[3];
#pragma unroll
                for (int nn = 0; nn < 4; nn++)
                    acc[mm][nn] = __builtin_amdgcn_mfma_f32_16x16x32_f16(v, bxr[nn], acc[mm][nn], 0, 0, 0);
            }
        }
    };

    XPREP(0);

    for (int t = 0; t < T_STEPS; t++) {
        const _Float16* cur = hbuf + (size_t)(t & 1) * HB;
        _Float16* nxt = hbuf + (size_t)((t + 1) & 1) * HB;

        // ---- h @ Wh: coherent (MALL) u64 atomic loads x2 per frag (proven) ----
#pragma unroll
        for (int j = 0; j < 4; j++) {
            int kb = ((2 + wave + 8 * j) << 2) + l4;  // 8..135
            unsigned long long* hp =
                (unsigned long long*)(cur + (((size_t)(kb - 8) << 8) + B0 + l15) * 8);
            half8 ah[4];
#pragma unroll
            for (int mm = 0; mm < 4; mm++) {
                union { unsigned long long u[2]; half8 h; } cv;
                cv.u[0] = __hip_atomic_load(hp + (mm << 5), __ATOMIC_RELAXED, __HIP_MEMORY_SCOPE_AGENT);
                cv.u[1] = __hip_atomic_load(hp + (mm << 5) + 1, __ATOMIC_RELAXED, __HIP_MEMORY_SCOPE_AGENT);
                ah[mm] = cv.h;
            }
#pragma unroll
            for (int mm = 0; mm < 4; mm++)
#pragma unroll
                for (int nn = 0; nn < 4; nn++)
                    acc[mm][nn] = __builtin_amdgcn_mfma_f32_16x16x32_f16(ah[mm], wfr[j][nn],
                                                                         acc[mm][nn], 0, 0, 0);
        }

        // ---- two-pass cross-wave reduction, 4 planes of 16KB, XOR-swizzled ----
        if (wave < 4) {
#pragma unroll
            for (int mm = 0; mm < 4; mm++)
#pragma unroll
                for (int nn = 0; nn < 4; nn++) {
                    int c = (nn << 4) + l15;
                    int bblk = (mm << 2) + l4;
                    int word = (((wave << 6) + c) << 6) + (((bblk ^ l15) & 15) << 2);
                    *(f32x4*)&P[word] = acc[mm][nn];
                }
        }
        __syncthreads();
        if (wave >= 4) {
            int pw = wave - 4;
#pragma unroll
            for (int mm = 0; mm < 4; mm++)
#pragma unroll
                for (int nn = 0; nn < 4; nn++) {
                    int c = (nn << 4) + l15;
                    int bblk = (mm << 2) + l4;
                    int word = (((pw << 6) + c) << 6) + (((bblk ^ l15) & 15) << 2);
                    f32x4 v = *(f32x4*)&P[word];
                    v += acc[mm][nn];
                    *(f32x4*)&P[word] = v;
                }
        }
        __syncthreads();

        // ---- activations: thread handles (b=bb, u=2*u0+q), q=0,1 ----
        union { _Float16 h2[2]; unsigned int u; } hs;
        float hvf[2];
#pragma unroll
        for (int q = 0; q < 2; q++) {
            int u = (u0 << 1) + q;
            float g4[4];
#pragma unroll
            for (int g = 0; g < 4; g++) {
                int c = (u << 2) + g;
                int word = (c << 6) + (((((bb >> 2) ^ c) & 15) << 2) | (bb & 3));
                float s = breg[q][g];
#pragma unroll
                for (int w = 0; w < 4; w++) s += P[(w << 12) + word];
                g4[g] = s;
            }
            float ig = sigm(g4[0]);
            float fg = sigm(g4[1]);
            float gg = tanh_fast(g4[2]);
            float og = sigm(g4[3]);
            float cv = fg * cst[q] + ig * gg;
            cst[q] = cv;
            float hv = og * tanh_fast(cv);
            hs.h2[q] = (_Float16)hv;
            hvf[q] = hv;
        }
        if (t == T_STEPS - 1) {
            int ug0 = (n << 4) + (u0 << 1);
            f32x2 hv2; hv2[0] = hvf[0]; hv2[1] = hvf[1];
            *(f32x2*)&hfinal[(size_t)(B0 + bb) * HID + ug0] = hv2;
            break;  // uniform; no h publish after last step
        }

        // ---- packed h publish: 4B -> overlay tile -> 128 threads x 2 u64 atomic stores ----
        __syncthreads();  // S_act: ALL P reads complete before overlay writes
        *(unsigned int*)&hstage[(bb << 4) + (u0 << 1)] = hs.u;
        __syncthreads();  // S_pack: overlay tile complete
        if (tid < 128) {
            int row = tid >> 1, hf = tid & 1;  // batch row, 8-unit half
            union { half8 h; unsigned long long u[2]; } v;
            v.h = *(const half8*)&hstage[(row << 4) + (hf << 3)];
            // dst: hbuf[nxt][kb'=2n+hf][B0+row][0..7] (16B, 8B-aligned)
            unsigned long long* dst =
                (unsigned long long*)(nxt + (((size_t)((n << 1) + hf) << 8) + B0 + row) * 8);
            __hip_atomic_store(dst, v.u[0], __ATOMIC_RELAXED, __HIP_MEMORY_SCOPE_AGENT);
            __hip_atomic_store(dst + 1, v.u[1], __ATOMIC_RELAXED, __HIP_MEMORY_SCOPE_AGENT);
        }
        asm volatile("s_waitcnt vmcnt(0)" ::: "memory");  // h(t) ack'd at MALL (proven)
        __syncthreads();  // S3a: all packed stores complete

        if (tid == 0)
            __hip_atomic_store(bar + (wg << 4), (unsigned int)(t + 1), __ATOMIC_RELAXED,
                               __HIP_MEMORY_SCOPE_AGENT);
        // reset acc and fold in x(t+1) while the m-group's producers arrive
#pragma unroll
        for (int i = 0; i < 4; i++)
#pragma unroll
            for (int j = 0; j < 4; j++) acc[i][j] = (f32x4){0.f, 0.f, 0.f, 0.f};
        XPREP(t + 1);
        // m-group-local barrier: one wave polls the group's 64 arrival words
        if (tid >= 256 && tid < 320) {
            const unsigned int* ap = bar + (((m << 6) + (tid - 256)) << 4);
            while (__hip_atomic_load(ap, __ATOMIC_RELAXED, __HIP_MEMORY_SCOPE_AGENT) <
                   (unsigned int)(t + 1)) {
                __builtin_amdgcn_s_sleep(1);
            }
        }
        __syncthreads();
    }
}

// out[b][j] = bout[j] + sum_k hfinal[b][k] * Wout[k][j]   (256 blocks x 64 threads)
__global__ void proj_kernel(const float* __restrict__ hfinal, const float* __restrict__ Wout,
                            const float* __restrict__ bout, float* __restrict__ out) {
    int b = blockIdx.x;
    int l = threadIdx.x;
    float acc[24];
#pragma unroll
    for (int j = 0; j < 24; j++) acc[j] = 0.f;
    for (int i = 0; i < 16; i++) {
        int k = i * 64 + l;
        float h = hfinal[(size_t)b * HID + k];
        const float* wr = Wout + (size_t)k * 24;
#pragma unroll
        for (int j = 0; j < 24; j++) acc[j] += h * wr[j];
    }
    __shared__ float red[24][65];
#pragma unroll
    for (int j = 0; j < 24; j++) red[j][l] = acc[j];
    __syncthreads();
    if (l < 24) {
        float s = bout[l];
#pragma unroll
        for (int i = 0; i < 64; i++) s += red[l][i];
        out[b * 24 + l] = s;
    }
}

extern "C" void kernel_launch(void* const* d_in, const int* in_sizes, int n_in,
                              void* d_out, int out_size, void* d_ws, size_t ws_size,
                              hipStream_t stream) {
    const float* x = (const float*)d_in[0];     // [256][512][64]
    const float* W = (const float*)d_in[1];     // [1088][4096]
    const float* b = (const float*)d_in[2];     // [4096]
    const float* Wout = (const float*)d_in[3];  // [1024][24]
    const float* bout = (const float*)d_in[4];  // [24]
    float* out = (float*)d_out;

    char* ws = (char*)d_ws;
    _Float16* Wp = (_Float16*)ws;                                 // 8,912,896 B
    _Float16* hbuf = (_Float16*)(ws + 8912896);                   // 1,048,576 B
    float* hfinal = (float*)(ws + 8912896 + 1048576);             // 1,048,576 B
    unsigned int* bar = (unsigned int*)(ws + 8912896 + 2097152);  // 16,384 B

    // zero h buffer 0 (h_init = 0) and barrier words, every call (graph-replay safe)
    hipMemsetAsync(hbuf, 0, (size_t)128 * 256 * 8 * sizeof(_Float16), stream);
    hipMemsetAsync(bar, 0, 16384, stream);

    pack_w<<<(64 * 136 * 64 + 255) / 256, 256, 0, stream>>>(W, Wp);

    void* args[6];
    args[0] = (void*)&x;
    args[1] = (void*)&Wp;
    args[2] = (void*)&b;
    args[3] = (void*)&hbuf;
    args[4] = (void*)&hfinal;
    args[5] = (void*)&bar;
    hipLaunchCooperativeKernel((void*)lstm_persist, dim3(GRID), dim3(NTHR), args, 0, stream);

    proj_kernel<<<256, 64, 0, stream>>>(hfinal, Wout, bout, out);
}